// Round 5
// baseline (231.201 us; speedup 1.0000x reference)
//
#include <hip/hip_runtime.h>
#include <stdint.h>

// Problem constants
#define D_DIM 512
#define K_CB  4096
#define N_TOK 16384
#define TOPK  8

// Fused kernel: 32 tokens/block, 512 threads (8 waves), 2 blocks/CU,
// 16 passes of 256 centroids (1 group of 32 per wave per pass)
#define TOKB  32
#define NPASS 16
#define NSEL  16   // fp8-selected candidates that get exact fp32 rescore (e fits 4 bits)

typedef __attribute__((ext_vector_type(4)))  int    i32x4;
typedef __attribute__((ext_vector_type(8)))  int    i32x8;
typedef __attribute__((ext_vector_type(16))) float  f32x16;
typedef __attribute__((ext_vector_type(4)))  float  f32x4;

// branchless top-N insert: N x (v_max_u32 + v_min_u32)
template<int N>
__device__ __forceinline__ void inskey(unsigned int k, unsigned int (&ts)[N]) {
    #pragma unroll
    for (int q = 0; q < N; ++q) {
        unsigned int hi = ts[q] > k ? ts[q] : k;
        unsigned int lo = ts[q] > k ? k : ts[q];
        ts[q] = hi; k = lo;
    }
}

// cbf8 = fp8(e4m3) of 64*codebook in 32x32x64-MFMA-A-fragment order, 16B-chunk-split:
// group g (32 rows), step s (64 k): 2048 B = [lo16B of lane 0..63][hi16B of lane 0..63],
// lane = (k>>5 within step)*32 + row, byte j = k&31.
// Full-GPU grid: 256 blocks x 16 rows, 8 float4 loads/thread.
__global__ __launch_bounds__(256) void conv_cb_kernel(
    const float* __restrict__ cb, unsigned char* __restrict__ cbf8,
    float* __restrict__ cnorm, float* __restrict__ loss,
    unsigned int* __restrict__ ticket) {
    const int t = threadIdx.x, gb = blockIdx.x;      // gb: 16-row block 0..255
    if (gb == 0 && t == 0) { *loss = 0.f; *ticket = 0u; }
    const int r16 = t >> 4, c = t & 15;              // row 0..15, 32-k chunk 0..15
    const int row = gb * 16 + r16;
    const float* src = cb + (size_t)row * D_DIM + c * 32;
    float sq = 0.f;
    unsigned int d[8];
    #pragma unroll
    for (int i = 0; i < 8; ++i) {
        float4 v = ((const float4*)src)[i];
        sq += v.x*v.x + v.y*v.y + v.z*v.z + v.w*v.w;
        int dd = __builtin_amdgcn_cvt_pk_fp8_f32(64.f * v.x, 64.f * v.y, 0, false);
        dd     = __builtin_amdgcn_cvt_pk_fp8_f32(64.f * v.z, 64.f * v.w, dd, true);
        d[i] = (unsigned int)dd;
    }
    sq += __shfl_down(sq, 8, 16);
    sq += __shfl_down(sq, 4, 16);
    sq += __shfl_down(sq, 2, 16);
    sq += __shfl_down(sq, 1, 16);
    if (c == 0) cnorm[row] = sq;                     // raw ||c||^2
    const int g = row >> 5, row32 = row & 31;
    const int s = c >> 1, khalf = c & 1;
    unsigned char* base = cbf8 + (size_t)g * 16384 + (size_t)s * 2048
                        + (size_t)(khalf * 32 + row32) * 16;
    i32x4 lo = {(int)d[0], (int)d[1], (int)d[2], (int)d[3]};   // j 0..15
    i32x4 hi = {(int)d[4], (int)d[5], (int)d[6], (int)d[7]};   // j 16..31
    *(i32x4*)(base)        = lo;
    *(i32x4*)(base + 1024) = hi;
}

// Fused: A = fp8(64c) centroids (coalesced fragment-ordered global), B = fp8(16x)
// tokens (LDS, conflict-free b128 reads), MX-scale MFMA K=64 unit scales.
// 512 threads / 32 tokens -> 2 blocks/CU so phases of co-resident blocks overlap
// (round-4 post-mortem: 1 block/CU serialized phase-homogeneous regions; pipes
// summed instead of overlapping). Per-lane selection split by pass parity keeps the
// r4-verified statistics: 32 lists/token x depth 8, 128 candidates/list.
__global__ __launch_bounds__(512, 4) void vq_fused(
    const float* __restrict__ x, const float* __restrict__ cb,
    const unsigned char* __restrict__ cbf8, const float* __restrict__ cnorm,
    float* __restrict__ out, float* __restrict__ loss_acc,
    unsigned int* __restrict__ ticket)
{
    __shared__ union {
        unsigned char xs8[TOKB * D_DIM];             // 16384 B: fp8(16x), B-fragment order
        unsigned int  keys[256 * 32];                // 32768 B: [list*8+e][token]
    } u;
    __shared__ float ncn[K_CB];                      // 16384 B: 32768 - 512*||c||^2
    __shared__ unsigned int pk[TOKB * 65];           // 8320 B: stage-1 partials (padded)
    __shared__ int   tki[TOKB * 17];                 // padded stride 17
    __shared__ float tks[TOKB * 17];
    __shared__ float tkw[TOKB * TOPK];
    __shared__ int   tkif[TOKB * TOPK];
    __shared__ float redbuf[8];

    const int t    = threadIdx.x;
    const int lane = t & 63;
    const int w    = t >> 6;          // wave 0..7
    const int m32  = lane & 31;
    const int half = lane >> 5;
    const int tok0 = blockIdx.x * TOKB;

    const char* cb8l = (const char*)cbf8 + (size_t)lane * 16;

    // ---- prefetch pass-0 A steps 0,1 (overlaps the staging barrier) ----
    i32x4 pf0l, pf0h, pf1l, pf1h;
    {
        const int p0  = (2 * w) & 15;
        const char* abp = cb8l + (size_t)(p0 * 8 + w) * 16384;
        pf0l = *(const i32x4*)(abp);
        pf0h = *(const i32x4*)(abp + 1024);
        pf1l = *(const i32x4*)(abp + 2048);
        pf1h = *(const i32x4*)(abp + 3072);
    }

    // ---- stage xs8 in B-fragment order (fp8 of 16*x), 16B-chunk-split ----
    {
        const int token = t >> 4, c = t & 15;        // 16 threads/token
        const int s2 = c >> 1, lh = c & 1;
        const f32x4* src = (const f32x4*)(x + (size_t)(tok0 + token) * D_DIM + c * 32);
        unsigned int d[8];
        #pragma unroll
        for (int i = 0; i < 8; ++i) {
            f32x4 v = src[i];
            int dd = __builtin_amdgcn_cvt_pk_fp8_f32(16.f * v.x, 16.f * v.y, 0, false);
            dd     = __builtin_amdgcn_cvt_pk_fp8_f32(16.f * v.z, 16.f * v.w, dd, true);
            d[i] = (unsigned int)dd;
        }
        unsigned char* base = u.xs8 + s2 * 2048 + (lh * 32 + token) * 16;
        i32x4 lo = {(int)d[0], (int)d[1], (int)d[2], (int)d[3]};   // j 0..15
        i32x4 hi = {(int)d[4], (int)d[5], (int)d[6], (int)d[7]};   // j 16..31
        *(i32x4*)(base)        = lo;
        *(i32x4*)(base + 1024) = hi;
    }
    {   // ncn = 32768 - 512*||c||^2 => key = 512*(2xc - ||c||^2) + 32768 > 0
        float4 v0 = ((const float4*)cnorm)[t];
        float4 v1 = ((const float4*)cnorm)[t + 512];
        float4 n0 = {32768.f - 512.f * v0.x, 32768.f - 512.f * v0.y,
                     32768.f - 512.f * v0.z, 32768.f - 512.f * v0.w};
        float4 n1 = {32768.f - 512.f * v1.x, 32768.f - 512.f * v1.y,
                     32768.f - 512.f * v1.z, 32768.f - 512.f * v1.w};
        *(float4*)&ncn[t * 4]         = n0;
        *(float4*)&ncn[(t + 512) * 4] = n1;
    }
    __syncthreads();

    unsigned int tsA[8], tsB[8];      // per-lane lists: even passes / odd passes
    #pragma unroll
    for (int i = 0; i < 8; ++i) { tsA[i] = 0u; tsB[i] = 0u; }

    const unsigned char* pb = u.xs8 + lane * 16;

    for (int pp = 0; pp < NPASS; ++pp) {
        const int p  = (pp + 2 * w) & 15;            // stagger waves across passes
        const int ga = p * 8 + w;                    // centroid 32-group 0..127
        f32x16 acc;
        #pragma unroll
        for (int g = 0; g < 4; ++g) {                // acc init (LDS bcast)
            float4 n0 = *(const float4*)&ncn[ga * 32 + g * 8 + 4 * half];
            acc[g*4+0]=n0.x; acc[g*4+1]=n0.y; acc[g*4+2]=n0.z; acc[g*4+3]=n0.w;
        }
        const char* ab = cb8l + (size_t)ga * 16384;
        __builtin_amdgcn_s_setprio(1);
        {   // steps 0,1 from prefetched A
            i32x4 bl0 = *(const i32x4*)(pb);
            i32x4 bh0 = *(const i32x4*)(pb + 1024);
            i32x8 A0 = __builtin_shufflevector(pf0l, pf0h, 0,1,2,3,4,5,6,7);
            i32x8 B0 = __builtin_shufflevector(bl0, bh0, 0,1,2,3,4,5,6,7);
            acc = __builtin_amdgcn_mfma_scale_f32_32x32x64_f8f6f4(
                      A0, B0, acc, 0, 0, 0, 0x7F7F7F7F, 0, 0x7F7F7F7F);
            i32x4 bl1 = *(const i32x4*)(pb + 2048);
            i32x4 bh1 = *(const i32x4*)(pb + 3072);
            i32x8 A1 = __builtin_shufflevector(pf1l, pf1h, 0,1,2,3,4,5,6,7);
            i32x8 B1 = __builtin_shufflevector(bl1, bh1, 0,1,2,3,4,5,6,7);
            acc = __builtin_amdgcn_mfma_scale_f32_32x32x64_f8f6f4(
                      A1, B1, acc, 0, 0, 0, 0x7F7F7F7F, 0, 0x7F7F7F7F);
        }
        #pragma unroll 2
        for (int s = 2; s < 8; ++s) {                // steps 2..7
            i32x4 al = *(const i32x4*)(ab + s * 2048);
            i32x4 ah = *(const i32x4*)(ab + s * 2048 + 1024);
            i32x4 bl = *(const i32x4*)(pb + s * 2048);
            i32x4 bh = *(const i32x4*)(pb + s * 2048 + 1024);
            i32x8 A = __builtin_shufflevector(al, ah, 0,1,2,3,4,5,6,7);
            i32x8 B = __builtin_shufflevector(bl, bh, 0,1,2,3,4,5,6,7);
            acc = __builtin_amdgcn_mfma_scale_f32_32x32x64_f8f6f4(
                      A, B, acc, 0, 0, 0, 0x7F7F7F7F, 0, 0x7F7F7F7F);
        }
        __builtin_amdgcn_s_setprio(0);
        if (pp < NPASS - 1) {                        // prefetch next pass steps 0,1;
            const int p2 = (pp + 1 + 2 * w) & 15;    // latency hidden under selection
            const char* abn = cb8l + (size_t)(p2 * 8 + w) * 16384;
            pf0l = *(const i32x4*)(abn);
            pf0h = *(const i32x4*)(abn + 1024);
            pf1l = *(const i32x4*)(abn + 2048);
            pf1h = *(const i32x4*)(abn + 3072);
        }
        // biased keys: scores ~[27e3,38e3] > 0 => uint-ordered; low 12 bits = 4095-idx
        const unsigned int K0 = 4095u - (unsigned int)(ga * 32) - 4u * (unsigned int)half;
        if ((pp & 1) == 0) {
            #pragma unroll
            for (int r = 0; r < 16; ++r) {
                const unsigned int cr = (unsigned int)((r & 3) + 8 * (r >> 2));
                inskey((__float_as_uint(acc[r]) & 0xFFFFF000u) | (K0 - cr), tsA);
            }
        } else {
            #pragma unroll
            for (int r = 0; r < 16; ++r) {
                const unsigned int cr = (unsigned int)((r & 3) + 8 * (r >> 2));
                inskey((__float_as_uint(acc[r]) & 0xFFFFF000u) | (K0 - cr), tsB);
            }
        }
    }

    // ---- epilogue ----
    __syncthreads();   // xs8 dead -> keys
    {
        const int L0 = w * 4 + half * 2;             // lists L0 (even), L0+1 (odd)
        #pragma unroll
        for (int e = 0; e < 8; ++e) {
            u.keys[(L0 * 8 + e) * 32 + m32]       = tsA[e];
            u.keys[((L0 + 1) * 8 + e) * 32 + m32] = tsB[e];
        }
    }
    __syncthreads();
    if (t < 128) {     // stage 1: 4 threads/token, 64 keys (8 lists) -> top-16 partials
        const int token = t >> 2, sub = t & 3;
        unsigned int bs[16];
        #pragma unroll
        for (int i = 0; i < 16; ++i) bs[i] = 0u;
        #pragma unroll 2
        for (int k = 0; k < 64; ++k) inskey(u.keys[(sub * 64 + k) * 32 + token], bs);
        #pragma unroll
        for (int e = 0; e < 16; ++e) pk[token * 65 + sub * 16 + e] = bs[e];
    }
    __syncthreads();
    if (t < TOKB) {    // stage 2: top-16 fp8 candidates, decode indices
        unsigned int bs[NSEL];
        #pragma unroll
        for (int i = 0; i < NSEL; ++i) bs[i] = 0u;
        #pragma unroll 2
        for (int k = 0; k < 64; ++k) inskey(pk[t * 65 + k], bs);
        #pragma unroll
        for (int r = 0; r < NSEL; ++r) tki[t * 17 + r] = 4095 - (int)(bs[r] & 0xFFFu);
    }
    __syncthreads();
    {   // exact fp32 rescore of 16 candidates: 16 threads/token, x row read ONCE,
        // two halves of 8 to bound register pressure; coalesced interleaved float4s
        const int token = t >> 4, sl = t & 15;
        const f32x4* xr = (const f32x4*)(x + (size_t)(tok0 + token) * D_DIM);
        f32x4 xv[8];
        #pragma unroll
        for (int i = 0; i < 8; ++i) xv[i] = xr[sl + 16 * i];
        #pragma unroll
        for (int hh = 0; hh < 2; ++hh) {
            float pd[8];
            #pragma unroll
            for (int e = 0; e < 8; ++e) {
                const int idx = tki[token * 17 + hh * 8 + e];
                const f32x4* cr = (const f32x4*)(cb + (size_t)idx * D_DIM);
                float dot = 0.f;
                #pragma unroll
                for (int i = 0; i < 8; ++i) {
                    f32x4 cv = cr[sl + 16 * i];
                    dot += xv[i].x*cv.x + xv[i].y*cv.y + xv[i].z*cv.z + xv[i].w*cv.w;
                }
                pd[e] = dot;
            }
            #pragma unroll
            for (int e = 0; e < 8; ++e) {
                pd[e] += __shfl_down(pd[e], 8, 16);
                pd[e] += __shfl_down(pd[e], 4, 16);
                pd[e] += __shfl_down(pd[e], 2, 16);
                pd[e] += __shfl_down(pd[e], 1, 16);
            }
            if (sl == 0) {
                #pragma unroll
                for (int e = 0; e < 8; ++e)
                    tks[token * 17 + hh * 8 + e] =
                        2.f * pd[e] - cnorm[tki[token * 17 + hh * 8 + e]];
            }
        }
    }
    __syncthreads();
    if (t < TOKB) {    // exact top-8 of the 16, softmax on exact scores
        unsigned int bs[8];
        #pragma unroll
        for (int i = 0; i < 8; ++i) bs[i] = 0u;
        #pragma unroll
        for (int e = 0; e < NSEL; ++e) {
            unsigned int uu = __float_as_uint(tks[t * 17 + e]);
            uu ^= (unsigned int)((int)uu >> 31) | 0x80000000u;   // monotone float->uint
            inskey((uu & 0xFFFFFFF0u) | (unsigned int)e, bs);
        }
        const float m = tks[t * 17 + (int)(bs[0] & 15u)];
        float wv[TOPK], sum = 0.f;
        int ids[TOPK];
        #pragma unroll
        for (int r = 0; r < TOPK; ++r) {
            const int e = (int)(bs[r] & 15u);
            wv[r] = __expf(tks[t * 17 + e] - m); sum += wv[r];
            ids[r] = tki[t * 17 + e];
        }
        const float inv = 1.f / sum;
        #pragma unroll
        for (int r = 0; r < TOPK; ++r) {
            tkw[t * TOPK + r] = wv[r] * inv;
            tkif[t * TOPK + r] = ids[r];
        }
    }
    __syncthreads();
    // output + loss partial
    float lsum = 0.f;
    #pragma unroll 1
    for (int it = 0; it < (TOKB * (D_DIM / 4)) / 512; ++it) {    // 8 iters
        const int p = it * 512 + t;
        const int token = p >> 7, d4 = p & 127;
        float4 q = {0.f, 0.f, 0.f, 0.f};
        #pragma unroll
        for (int e = 0; e < TOPK; ++e) {
            const float wv = tkw[token * TOPK + e];
            const int  idx = tkif[token * TOPK + e];
            const float4 cv = ((const float4*)cb)[(size_t)idx * (D_DIM / 4) + d4];
            q.x += wv * cv.x; q.y += wv * cv.y; q.z += wv * cv.z; q.w += wv * cv.w;
        }
        const size_t go = (size_t)(tok0 + token) * (D_DIM / 4) + d4;
        f32x4 xv = __builtin_nontemporal_load((const f32x4*)x + go);
        const float ex = q.x - xv.x, ey = q.y - xv.y, ez = q.z - xv.z, ew = q.w - xv.w;
        lsum += ex*ex + ey*ey + ez*ez + ew*ew;
        f32x4 qv = {q.x, q.y, q.z, q.w};
        __builtin_nontemporal_store(qv, (f32x4*)out + go);
    }
    #pragma unroll
    for (int off = 32; off > 0; off >>= 1) lsum += __shfl_down(lsum, off, 64);
    if (lane == 0) redbuf[w] = lsum;
    __syncthreads();
    if (t == 0) {
        float s = 0.f;
        #pragma unroll
        for (int i = 0; i < 8; ++i) s += redbuf[i];
        atomicAdd(loss_acc, s);
        __threadfence();
        unsigned int prev = atomicAdd(ticket, 1u);
        if (prev == (unsigned int)(gridDim.x - 1)) {   // last block finalizes loss
            __threadfence();
            float total = atomicAdd(loss_acc, 0.f);    // coherent read
            out[(size_t)N_TOK * D_DIM] = 1.25f * total / (float)((size_t)N_TOK * D_DIM);
        }
    }
}

extern "C" void kernel_launch(void* const* d_in, const int* in_sizes, int n_in,
                              void* d_out, int out_size, void* d_ws, size_t ws_size,
                              hipStream_t stream) {
    const float* x  = (const float*)d_in[0];   // [8,2048,512] fp32
    const float* cb = (const float*)d_in[1];   // [4096,512] fp32
    float* out = (float*)d_out;

    char* ws = (char*)d_ws;
    unsigned char* cbf8   = (unsigned char*)ws;              // 2 MB, fp8 fragment-ordered
    float*         cnorm  = (float*)(ws + 2097152);          // 16 KB
    float*         loss   = (float*)(ws + 2113536);          // 4 B
    unsigned int*  ticket = (unsigned int*)(ws + 2113600);   // 4 B

    conv_cb_kernel<<<256, 256, 0, stream>>>(cb, cbf8, cnorm, loss, ticket);
    vq_fused<<<N_TOK / TOKB, 512, 0, stream>>>(x, cb, cbf8, cnorm, out, loss, ticket);
}